// Round 4
// baseline (163.589 us; speedup 1.0000x reference)
//
#include <hip/hip_runtime.h>
#include <math.h>

#define CC 512
#define HH 38
#define WW 63
#define HWSZ (HH * WW)
#define NROIS 1024
#define NP 49            // 7x7 pooled positions

typedef float f32x4 __attribute__((ext_vector_type(4)));

static __device__ __forceinline__ f32x4 splat4(float v) {
    f32x4 r; r[0] = v; r[1] = v; r[2] = v; r[3] = v; return r;
}

// ---------------- LDS-tiled transpose: CHW (512, 2394) -> HWC (2394, 512) ----
__global__ __launch_bounds__(256) void transpose_tiled(
        const float* __restrict__ src, float* __restrict__ dst) {
    __shared__ float tile[64][65];
    int s0 = blockIdx.x * 64;
    int c0 = blockIdx.y * 64;
    int tx = threadIdx.x & 63;
    int ty = threadIdx.x >> 6;

#pragma unroll
    for (int k = 0; k < 16; ++k) {
        int c = ty * 16 + k;
        int s = s0 + tx;
        float v = (s < HWSZ) ? src[(c0 + c) * HWSZ + s] : 0.0f;
        tile[tx][c] = v;
    }
    __syncthreads();
#pragma unroll
    for (int k = 0; k < 16; ++k) {
        int s = ty * 16 + k;
        if (s0 + s < HWSZ)
            dst[(s0 + s) * CC + c0 + tx] = tile[s][tx];
    }
}

// ---------------- main kernel v9 ---------------------------------------------
// v7/v8 structure (quarter-roi, 256 thr, lane g = channel-quad, slot s =
// output row, channel-major stride-49 stage, linear nontemporal flush).
// v8 post-mortem: VGPR=48 proved the compiler re-sank the 16-load batch to
// ~5 in flight (register minimization beats source order). v9 forces MLP:
// the 28 samples become 14 units of 8 gathers (one sample-column pair);
// double-buffered rotating pipeline: issue unit u+1's 8 loads, then
// sched_barrier(0) (hard fence -- scheduler cannot sink the loads below),
// then compute unit u from the other parity buffer. Steady state: 8 loads
// in flight DURING every compute burst, counted vmcnt(8) waits, per-wave
// MLP ~8-16 continuously. buf[2][8] parity-indexed in a fully-unrolled
// loop -> all indices compile-time (no scratch). No min-waves clamp: let
// RA take ~110-130 VGPR (3-4 waves/SIMD, >= current effective 3.6).
__global__ __launch_bounds__(256) void roi_pool_v9(
        const float* __restrict__ img,    // HWC (2394, 512)
        const float* __restrict__ rois,   // (N, 5)
        float* __restrict__ out) {        // (N, 512, 7, 7)
    __shared__ float stage[128 * NP];     // 25088 B

    int n = blockIdx.x >> 2;              // wave-uniform
    int q = blockIdx.x & 3;
    int t = threadIdx.x;
    int g = t & 31;                       // channel-quad within quarter
    int s = t >> 5;                       // row slot 0..7 (slot 7 idle)

    const float* r = rois + n * 5;
    float x1n = (r[1] * 0.0625f) / 62.0f;
    float y1n = (r[2] * 0.0625f) / 37.0f;
    float x2n = (r[3] * 0.0625f) / 62.0f;
    float y2n = (r[4] * 0.0625f) / 37.0f;
    float ydn = y2n - y1n;
    float xdn = x2n - x1n;

    if (s < 7) {
        int oy = s;
        const f32x4* img4 = (const f32x4*)img + (q << 5) + g;

        // y-params for the two sample rows of this output row (slot-divergent)
        float wy0, wy1; int yA0, yB0, yA1, yB1; bool vy0, vy1;
        {
            float tty = (float)(oy * 2) * (1.0f / 13.0f);
            float in_y = (y1n + tty * ydn) * 37.0f;
            vy0 = (in_y >= 0.0f) && (in_y <= 37.0f);
            float y0f = floorf(in_y);
            wy0 = in_y - y0f;
            yA0 = (int)fminf(fmaxf(y0f, 0.0f), 37.0f) * (WW * (CC / 4));
            yB0 = (int)fminf(fmaxf(y0f + 1.0f, 0.0f), 37.0f) * (WW * (CC / 4));
        }
        {
            float tty = (float)(oy * 2 + 1) * (1.0f / 13.0f);
            float in_y = (y1n + tty * ydn) * 37.0f;
            vy1 = (in_y >= 0.0f) && (in_y <= 37.0f);
            float y0f = floorf(in_y);
            wy1 = in_y - y0f;
            yA1 = (int)fminf(fmaxf(y0f, 0.0f), 37.0f) * (WW * (CC / 4));
            yB1 = (int)fminf(fmaxf(y0f + 1.0f, 0.0f), 37.0f) * (WW * (CC / 4));
        }

        int sbase = g * (4 * NP) + oy * 7;   // stage float base for channel 4g

        // x-param for sample column ixx (block-uniform values)
        auto xp = [&](int ixx, float& wx, int& o0, int& o1, bool& vx) {
            float ttx = (float)ixx * (1.0f / 13.0f);
            float in_x = (x1n + ttx * xdn) * 62.0f;
            vx = (in_x >= 0.0f) && (in_x <= 62.0f);
            float x0f = floorf(in_x);
            wx = in_x - x0f;
            o0 = (int)fminf(fmaxf(x0f, 0.0f), 62.0f) << 7;        // * CC/4
            o1 = (int)fminf(fmaxf(x0f + 1.0f, 0.0f), 62.0f) << 7;
        };

        // issue the 8 corner gathers of one sample column into buffer b
        f32x4 buf[2][8];
        float wxu[2]; bool vxu[2];

        {   // prologue: unit 0 -> buf[0]
            float wx; int o0, o1; bool vx;
            xp(0, wx, o0, o1, vx);
            buf[0][0] = img4[yA0 + o0];
            buf[0][1] = img4[yA0 + o1];
            buf[0][2] = img4[yB0 + o0];
            buf[0][3] = img4[yB0 + o1];
            buf[0][4] = img4[yA1 + o0];
            buf[0][5] = img4[yA1 + o1];
            buf[0][6] = img4[yB1 + o0];
            buf[0][7] = img4[yB1 + o1];
            wxu[0] = wx; vxu[0] = vx;
        }

        f32x4 acc = splat4(-INFINITY);

#pragma unroll
        for (int u = 0; u < 14; ++u) {
            const int b = u & 1;
            // ---- issue next unit's 8 loads into the other buffer ----
            if (u < 13) {
                float wx; int o0, o1; bool vx;
                xp(u + 1, wx, o0, o1, vx);
                buf[b ^ 1][0] = img4[yA0 + o0];
                buf[b ^ 1][1] = img4[yA0 + o1];
                buf[b ^ 1][2] = img4[yB0 + o0];
                buf[b ^ 1][3] = img4[yB0 + o1];
                buf[b ^ 1][4] = img4[yA1 + o0];
                buf[b ^ 1][5] = img4[yA1 + o1];
                buf[b ^ 1][6] = img4[yB1 + o0];
                buf[b ^ 1][7] = img4[yB1 + o1];
                wxu[b ^ 1] = wx; vxu[b ^ 1] = vx;
            }
            // hard fence: loads above may not sink below this point
            __builtin_amdgcn_sched_barrier(0);

            // ---- compute unit u from buf[b] (waits vmcnt(8), not 0) ----
            float wx = wxu[b]; bool vx = vxu[b];
            {
                f32x4 top = buf[b][0] + (buf[b][1] - buf[b][0]) * wx;
                f32x4 bot = buf[b][2] + (buf[b][3] - buf[b][2]) * wx;
                f32x4 val = top + (bot - top) * wy0;
                val = (vx && vy0) ? val : splat4(0.0f);
#pragma unroll
                for (int j = 0; j < 4; ++j) acc[j] = fmaxf(acc[j], val[j]);
            }
            {
                f32x4 top = buf[b][4] + (buf[b][5] - buf[b][4]) * wx;
                f32x4 bot = buf[b][6] + (buf[b][7] - buf[b][6]) * wx;
                f32x4 val = top + (bot - top) * wy1;
                val = (vx && vy1) ? val : splat4(0.0f);
#pragma unroll
                for (int j = 0; j < 4; ++j) acc[j] = fmaxf(acc[j], val[j]);
            }

            // ---- end of an output position (odd unit): stage + reset ----
            if (u & 1) {
                int ox = u >> 1;
                stage[sbase + ox         ] = acc[0];
                stage[sbase + ox + NP    ] = acc[1];
                stage[sbase + ox + 2 * NP] = acc[2];
                stage[sbase + ox + 3 * NP] = acc[3];
                acc = splat4(-INFINITY);
            }
        }
    }

    __syncthreads();

    // linear flush: stage float layout == output layout for this quarter.
    const f32x4* s4 = (const f32x4*)stage;
    f32x4* o4 = (f32x4*)(out + ((n << 9) + (q << 7)) * NP);
    for (int i = t; i < (128 * NP) / 4; i += 256)
        __builtin_nontemporal_store(s4[i], &o4[i]);
}

// ---------------- fallback (ws too small): direct CHW gathers ----------------
__global__ __launch_bounds__(256) void roi_pool_chw(
        const float* __restrict__ img,    // CHW
        const float* __restrict__ rois,
        float* __restrict__ out) {
    __shared__ float stage[256 * NP];
    int n = blockIdx.x >> 1;
    int h = blockIdx.x & 1;
    int t = threadIdx.x;
    int c = (h << 8) + t;

    const float* r = rois + n * 5;
    float x1n = (r[1] * 0.0625f) / 62.0f;
    float y1n = (r[2] * 0.0625f) / 37.0f;
    float x2n = (r[3] * 0.0625f) / 62.0f;
    float y2n = (r[4] * 0.0625f) / 37.0f;
    float ydn = y2n - y1n;
    float xdn = x2n - x1n;

    const float* imgc = img + c * HWSZ;

    float wxa[14];
    int   x0a[14], x1a[14];
    int   vxm = 0;
#pragma unroll
    for (int ix = 0; ix < 14; ++ix) {
        float tt = (float)ix * (1.0f / 13.0f);
        float in_x = (x1n + tt * xdn) * 62.0f;
        if (in_x >= 0.0f && in_x <= 62.0f) vxm |= (1 << ix);
        float x0f = floorf(in_x);
        wxa[ix] = in_x - x0f;
        x0a[ix] = (int)fminf(fmaxf(x0f, 0.0f), 62.0f);
        x1a[ix] = (int)fminf(fmaxf(x0f + 1.0f, 0.0f), 62.0f);
    }

#pragma unroll
    for (int oy = 0; oy < 7; ++oy) {
        float row[7];
#pragma unroll
        for (int ox = 0; ox < 7; ++ox) row[ox] = -INFINITY;
#pragma unroll
        for (int sy = 0; sy < 2; ++sy) {
            int iy = oy * 2 + sy;
            float tt = (float)iy * (1.0f / 13.0f);
            float in_y = (y1n + tt * ydn) * 37.0f;
            bool vy = (in_y >= 0.0f) && (in_y <= 37.0f);
            float y0f = floorf(in_y);
            float wy = in_y - y0f;
            int yy0 = (int)fminf(fmaxf(y0f, 0.0f), 37.0f);
            int yy1 = (int)fminf(fmaxf(y0f + 1.0f, 0.0f), 37.0f);
            int yb0 = yy0 * WW;
            int yb1 = yy1 * WW;
#pragma unroll
            for (int ox = 0; ox < 7; ++ox) {
#pragma unroll
                for (int sx = 0; sx < 2; ++sx) {
                    int ix = ox * 2 + sx;
                    float g00 = imgc[yb0 + x0a[ix]];
                    float g01 = imgc[yb0 + x1a[ix]];
                    float g10 = imgc[yb1 + x0a[ix]];
                    float g11 = imgc[yb1 + x1a[ix]];
                    float wx = wxa[ix];
                    float top = g00 + (g01 - g00) * wx;
                    float bot = g10 + (g11 - g10) * wx;
                    float val = top + (bot - top) * wy;
                    bool valid = vy && ((vxm >> ix) & 1);
                    val = valid ? val : 0.0f;
                    row[ox] = fmaxf(row[ox], val);
                }
            }
        }
#pragma unroll
        for (int ox = 0; ox < 7; ++ox)
            stage[t * NP + oy * 7 + ox] = row[ox];
    }

    __syncthreads();
    const float4* s4 = (const float4*)stage;
    float4* o4 = (float4*)(out + ((n << 9) + (h << 8)) * NP);
    for (int i = t; i < (256 * NP) / 4; i += 256)
        o4[i] = s4[i];
}

extern "C" void kernel_launch(void* const* d_in, const int* in_sizes, int n_in,
                              void* d_out, int out_size, void* d_ws, size_t ws_size,
                              hipStream_t stream) {
    const float* bottom = (const float*)d_in[0];
    const float* rois   = (const float*)d_in[1];
    float* out = (float*)d_out;

    const size_t need = (size_t)CC * HWSZ * sizeof(float);  // ~4.9 MB
    if (ws_size >= need) {
        float* img = (float*)d_ws;
        dim3 tg((HWSZ + 63) / 64, CC / 64);   // 38 x 8
        transpose_tiled<<<tg, 256, 0, stream>>>(bottom, img);
        roi_pool_v9<<<NROIS * 4, 256, 0, stream>>>(img, rois, out);
    } else {
        roi_pool_chw<<<NROIS * 2, 256, 0, stream>>>(bottom, rois, out);
    }
}

// Round 5
// 162.656 us; speedup vs baseline: 1.0057x; 1.0057x over previous
//
#include <hip/hip_runtime.h>
#include <math.h>

#define CC 512
#define HH 38
#define WW 63
#define HWSZ (HH * WW)
#define NROIS 1024
#define NP 49              // 7x7 pooled positions
#define CHUNK 132          // floats per (iy,ox) chunk: 128 ch + 4 pad (bank skew)

typedef float   f32x4 __attribute__((ext_vector_type(4)));
typedef _Float16 f16x8 __attribute__((ext_vector_type(8)));
typedef _Float16 f16x2 __attribute__((ext_vector_type(2)));

// ------------- transpose + convert: CHW f32 (512,2394) -> HWC fp16 (2394,512)
__global__ __launch_bounds__(256) void transpose_cvt(
        const float* __restrict__ src, _Float16* __restrict__ dst) {
    __shared__ float tile[64][65];
    int s0 = blockIdx.x * 64;
    int c0 = blockIdx.y * 64;
    int tx = threadIdx.x & 63;
    int ty = threadIdx.x >> 6;

#pragma unroll
    for (int k = 0; k < 16; ++k) {
        int c = ty * 16 + k;
        int s = s0 + tx;
        float v = (s < HWSZ) ? src[(c0 + c) * HWSZ + s] : 0.0f;
        tile[tx][c] = v;
    }
    __syncthreads();

    // store phase: half2 stores, 32 c-pairs x 8 row-groups
    int u = threadIdx.x & 31;       // channel pair
    int vv = threadIdx.x >> 5;      // row group
#pragma unroll
    for (int k = 0; k < 8; ++k) {
        int s = vv * 8 + k;
        if (s0 + s < HWSZ) {
            f16x2 h;
            h[0] = (_Float16)tile[s][2 * u];
            h[1] = (_Float16)tile[s][2 * u + 1];
            *(f16x2*)(dst + (size_t)(s0 + s) * CC + c0 + 2 * u) = h;
        }
    }
}

// ---------------- main kernel v10 --------------------------------------------
// Diagnosis after v7/v8/v9 all flat at 65us: gather stream = 1.64 GB through
// L1<->L2 in 65us = 25 TB/s ~ 73% of the L2 ceiling -> L2-gather-BYTE bound;
// schedule/MLP changes can't help, only fewer bytes. v10: image stored fp16
// (2.45 MB -> fits ONE XCD's 4MB L2; no L3 traffic) and each lane owns 8
// channels: one 16B f16x8 load / corner = HALF the bytes AND half the load
// instructions at the same coalescing. Block = quarter roi (128 ch = 16 octs),
// lane g = t&15 = channel oct, slot = t>>4 in [0,16): slot = SAMPLE ROW iy
// (14 active of 16). sx-max in-thread; sy-max (iy pairs) folded into the
// flush via LDS. X-lerp packed f16 (v_pk_*, 2ch/op), y-lerp f32 -> VALU per
// thread ~= v7 despite 8ch/lane. Stage chunk stride 132 floats skews banks
// (per-ox +4, per-iy +28) -> <=2-way on ds_write_b128 (free per m136).
__global__ __launch_bounds__(256) void roi_pool_v10(
        const _Float16* __restrict__ img,  // HWC fp16 (2394, 512)
        const float* __restrict__ rois,    // (N, 5)
        float* __restrict__ out) {         // (N, 512, 7, 7)
    __shared__ float stage[14 * 7 * CHUNK];   // 51744 B -> 3 blocks/CU

    int n = blockIdx.x >> 2;              // wave-uniform
    int q = blockIdx.x & 3;
    int t = threadIdx.x;
    int g = t & 15;                       // channel oct within quarter
    int slot = t >> 4;                    // 0..15; slots 0..13 = sample row iy

    const float* r = rois + n * 5;
    float x1n = (r[1] * 0.0625f) / 62.0f;
    float y1n = (r[2] * 0.0625f) / 37.0f;
    float x2n = (r[3] * 0.0625f) / 62.0f;
    float y2n = (r[4] * 0.0625f) / 37.0f;
    float ydn = y2n - y1n;
    float xdn = x2n - x1n;

    if (slot < 14) {
        int iy = slot;
        // this slot's y-params (one sample row)
        float tty = (float)iy * (1.0f / 13.0f);
        float in_y = (y1n + tty * ydn) * 37.0f;
        bool vy = (in_y >= 0.0f) && (in_y <= 37.0f);
        float y0f = floorf(in_y);
        float wy = in_y - y0f;
        int yb0 = (int)fminf(fmaxf(y0f, 0.0f), 37.0f) * (WW * CC);        // halfs
        int yb1 = (int)fminf(fmaxf(y0f + 1.0f, 0.0f), 37.0f) * (WW * CC);

        const _Float16* imgc = img + (q << 7) + (g << 3);   // +q*128 +8g halfs

        float acc[8];
#pragma unroll
        for (int j = 0; j < 8; ++j) acc[j] = -INFINITY;

#pragma unroll
        for (int ix = 0; ix < 14; ++ix) {
            // x-params (block-uniform values)
            float ttx = (float)ix * (1.0f / 13.0f);
            float in_x = (x1n + ttx * xdn) * 62.0f;
            bool vx = (in_x >= 0.0f) && (in_x <= 62.0f);
            float x0f = floorf(in_x);
            float wx = in_x - x0f;
            int xo0 = (int)fminf(fmaxf(x0f, 0.0f), 62.0f) << 9;           // *512
            int xo1 = (int)fminf(fmaxf(x0f + 1.0f, 0.0f), 62.0f) << 9;

            // 4 corner gathers, 16B each (8 ch fp16)
            f16x8 g00 = *(const f16x8*)(imgc + yb0 + xo0);
            f16x8 g01 = *(const f16x8*)(imgc + yb0 + xo1);
            f16x8 g10 = *(const f16x8*)(imgc + yb1 + xo0);
            f16x8 g11 = *(const f16x8*)(imgc + yb1 + xo1);

            // packed-f16 x-lerp (v_pk_*: 2 ch/op), f32 y-lerp
            _Float16 wxh = (_Float16)wx;
            f16x8 toph = g00 + (g01 - g00) * wxh;
            f16x8 both = g10 + (g11 - g10) * wxh;

            bool valid = vx && vy;
#pragma unroll
            for (int j = 0; j < 8; ++j) {
                float tf = (float)toph[j];
                float bf = (float)both[j];
                float val = tf + (bf - tf) * wy;
                val = valid ? val : 0.0f;
                acc[j] = fmaxf(acc[j], val);
            }

            if (ix & 1) {   // finished an output column pair -> stage + reset
                int ox = ix >> 1;
                int base = (iy * 7 + ox) * CHUNK + (g << 3);
                f32x4 a, b;
#pragma unroll
                for (int j = 0; j < 4; ++j) { a[j] = acc[j]; b[j] = acc[j + 4]; }
                *(f32x4*)(stage + base)     = a;
                *(f32x4*)(stage + base + 4) = b;
#pragma unroll
                for (int j = 0; j < 8; ++j) acc[j] = -INFINITY;
            }
        }
    }

    __syncthreads();

    // flush: sy-max (iy pairs 2oy / 2oy+1) + dense nontemporal float4 stores.
    // quarter region = 128 ch * 49 = 1568 float4.
    f32x4* o4 = (f32x4*)(out + ((n << 9) + (q << 7)) * NP);
    for (int i = t; i < (128 * NP) / 4; i += 256) {
        int m = i << 2;
        f32x4 v;
#pragma unroll
        for (int j = 0; j < 4; ++j) {
            int mm = m + j;
            int c  = mm / 49;             // local channel 0..127
            int p  = mm - c * 49;         // pooled position 0..48
            int oy = p / 7;
            int ox = p - oy * 7;
            int base = (14 * oy + ox) * CHUNK + c;   // iy=2oy chunk
            v[j] = fmaxf(stage[base], stage[base + 7 * CHUNK]);  // iy=2oy+1
        }
        __builtin_nontemporal_store(v, &o4[i]);
    }
}

// ---------------- fallback (ws too small): direct CHW f32 gathers ------------
__global__ __launch_bounds__(256) void roi_pool_chw(
        const float* __restrict__ img,    // CHW
        const float* __restrict__ rois,
        float* __restrict__ out) {
    __shared__ float stage[256 * NP];
    int n = blockIdx.x >> 1;
    int h = blockIdx.x & 1;
    int t = threadIdx.x;
    int c = (h << 8) + t;

    const float* r = rois + n * 5;
    float x1n = (r[1] * 0.0625f) / 62.0f;
    float y1n = (r[2] * 0.0625f) / 37.0f;
    float x2n = (r[3] * 0.0625f) / 62.0f;
    float y2n = (r[4] * 0.0625f) / 37.0f;
    float ydn = y2n - y1n;
    float xdn = x2n - x1n;

    const float* imgc = img + c * HWSZ;

    float wxa[14];
    int   x0a[14], x1a[14];
    int   vxm = 0;
#pragma unroll
    for (int ix = 0; ix < 14; ++ix) {
        float tt = (float)ix * (1.0f / 13.0f);
        float in_x = (x1n + tt * xdn) * 62.0f;
        if (in_x >= 0.0f && in_x <= 62.0f) vxm |= (1 << ix);
        float x0f = floorf(in_x);
        wxa[ix] = in_x - x0f;
        x0a[ix] = (int)fminf(fmaxf(x0f, 0.0f), 62.0f);
        x1a[ix] = (int)fminf(fmaxf(x0f + 1.0f, 0.0f), 62.0f);
    }

#pragma unroll
    for (int oy = 0; oy < 7; ++oy) {
        float row[7];
#pragma unroll
        for (int ox = 0; ox < 7; ++ox) row[ox] = -INFINITY;
#pragma unroll
        for (int sy = 0; sy < 2; ++sy) {
            int iy = oy * 2 + sy;
            float tt = (float)iy * (1.0f / 13.0f);
            float in_y = (y1n + tt * ydn) * 37.0f;
            bool vy = (in_y >= 0.0f) && (in_y <= 37.0f);
            float y0f = floorf(in_y);
            float wy = in_y - y0f;
            int yy0 = (int)fminf(fmaxf(y0f, 0.0f), 37.0f);
            int yy1 = (int)fminf(fmaxf(y0f + 1.0f, 0.0f), 37.0f);
            int yb0 = yy0 * WW;
            int yb1 = yy1 * WW;
#pragma unroll
            for (int ox = 0; ox < 7; ++ox) {
#pragma unroll
                for (int sx = 0; sx < 2; ++sx) {
                    int ix = ox * 2 + sx;
                    float g00 = imgc[yb0 + x0a[ix]];
                    float g01 = imgc[yb0 + x1a[ix]];
                    float g10 = imgc[yb1 + x0a[ix]];
                    float g11 = imgc[yb1 + x1a[ix]];
                    float wx = wxa[ix];
                    float top = g00 + (g01 - g00) * wx;
                    float bot = g10 + (g11 - g10) * wx;
                    float val = top + (bot - top) * wy;
                    bool valid = vy && ((vxm >> ix) & 1);
                    val = valid ? val : 0.0f;
                    row[ox] = fmaxf(row[ox], val);
                }
            }
        }
#pragma unroll
        for (int ox = 0; ox < 7; ++ox)
            stage[t * NP + oy * 7 + ox] = row[ox];
    }

    __syncthreads();
    const float4* s4 = (const float4*)stage;
    float4* o4 = (float4*)(out + ((n << 9) + (h << 8)) * NP);
    for (int i = t; i < (256 * NP) / 4; i += 256)
        o4[i] = s4[i];
}

extern "C" void kernel_launch(void* const* d_in, const int* in_sizes, int n_in,
                              void* d_out, int out_size, void* d_ws, size_t ws_size,
                              hipStream_t stream) {
    const float* bottom = (const float*)d_in[0];
    const float* rois   = (const float*)d_in[1];
    float* out = (float*)d_out;

    const size_t need = (size_t)CC * HWSZ * sizeof(_Float16);  // ~2.45 MB
    if (ws_size >= need) {
        _Float16* img = (_Float16*)d_ws;
        dim3 tg((HWSZ + 63) / 64, CC / 64);   // 38 x 8
        transpose_cvt<<<tg, 256, 0, stream>>>(bottom, img);
        roi_pool_v10<<<NROIS * 4, 256, 0, stream>>>(img, rois, out);
    } else {
        roi_pool_chw<<<NROIS * 2, 256, 0, stream>>>(bottom, rois, out);
    }
}

// Round 6
// 153.217 us; speedup vs baseline: 1.0677x; 1.0616x over previous
//
#include <hip/hip_runtime.h>
#include <math.h>

#define CC 512
#define HH 38
#define WW 63
#define HWSZ (HH * WW)
#define NROIS 1024
#define NP 49              // 7x7 pooled positions

typedef float    f32x4 __attribute__((ext_vector_type(4)));
typedef _Float16 f16x8 __attribute__((ext_vector_type(8)));
typedef _Float16 f16x2 __attribute__((ext_vector_type(2)));

// ------------- transpose + convert: CHW f32 (512,2394) -> HWC fp16 (2394,512)
__global__ __launch_bounds__(256) void transpose_cvt(
        const float* __restrict__ src, _Float16* __restrict__ dst) {
    __shared__ float tile[64][65];
    int s0 = blockIdx.x * 64;
    int c0 = blockIdx.y * 64;
    int tx = threadIdx.x & 63;
    int ty = threadIdx.x >> 6;

#pragma unroll
    for (int k = 0; k < 16; ++k) {
        int c = ty * 16 + k;
        int s = s0 + tx;
        float v = (s < HWSZ) ? src[(c0 + c) * HWSZ + s] : 0.0f;
        tile[tx][c] = v;
    }
    __syncthreads();

    int u = threadIdx.x & 31;       // channel pair
    int vv = threadIdx.x >> 5;      // row group
#pragma unroll
    for (int k = 0; k < 8; ++k) {
        int s = vv * 8 + k;
        if (s0 + s < HWSZ) {
            f16x2 h;
            h[0] = (_Float16)tile[s][2 * u];
            h[1] = (_Float16)tile[s][2 * u + 1];
            *(f16x2*)(dst + (size_t)(s0 + s) * CC + c0 + 2 * u) = h;
        }
    }
}

// ---------------- main kernel v11 --------------------------------------------
// v10 post-mortem: VALU-issue bound (VALUBusy 81% at occupancy 28%); the fat
// was (a) flush magic-division index math (~400 VALU/thread) + 3.2M bank-
// conflict cycles, (b) 52KB LDS -> 28% occupancy, (c) per-element validity
// cndmask. v11, same bytes & same numerics as v10:
//  - sy-max via __shfl_xor(.,16): slot pairs (iy, iy^1) are lanes l, l^16 of
//    the SAME wave (ds_swizzle: LDS pipe, off the VALU). Even slots write the
//    final output value into a stage that is ALREADY output-layout [128][49],
//    so the flush is a pure linear float4 copy (~50 VALU, ~0 conflicts).
//  - LDS 52->25 KB: 6 blocks/CU, occupancy back to ~50%.
//  - validity hoisted to a uniform branch around load+lerp+max (saves the
//    8 cndmask/ix and skips everything for OOB rows); the reference's
//    "invalid samples contribute 0 to the max" is recovered by a rare
//    acc=max(acc,0) once per output pair.
__global__ __launch_bounds__(256) void roi_pool_v11(
        const _Float16* __restrict__ img,  // HWC fp16 (2394, 512)
        const float* __restrict__ rois,    // (N, 5)
        float* __restrict__ out) {         // (N, 512, 7, 7)
    __shared__ float stage[128 * NP];      // 25088 B, output layout [c][p]

    int n = blockIdx.x >> 2;              // wave-uniform
    int q = blockIdx.x & 3;
    int t = threadIdx.x;
    int g = t & 15;                       // channel oct within quarter
    int slot = t >> 4;                    // 0..15; slots 0..13 = sample row iy

    const float* r = rois + n * 5;
    float x1n = (r[1] * 0.0625f) / 62.0f;
    float y1n = (r[2] * 0.0625f) / 37.0f;
    float x2n = (r[3] * 0.0625f) / 62.0f;
    float y2n = (r[4] * 0.0625f) / 37.0f;
    float ydn = y2n - y1n;
    float xdn = x2n - x1n;

    if (slot < 14) {
        int iy = slot;
        int oy = iy >> 1;
        // this slot's y-params (one sample row)
        float tty = (float)iy * (1.0f / 13.0f);
        float in_y = (y1n + tty * ydn) * 37.0f;
        bool vy = (in_y >= 0.0f) && (in_y <= 37.0f);
        float y0f = floorf(in_y);
        float wy = in_y - y0f;
        int yb0 = (int)fminf(fmaxf(y0f, 0.0f), 37.0f) * (WW * CC);        // halfs
        int yb1 = (int)fminf(fmaxf(y0f + 1.0f, 0.0f), 37.0f) * (WW * CC);

        const _Float16* imgc = img + (q << 7) + (g << 3);   // +q*128 +8g halfs

#pragma unroll
        for (int ox = 0; ox < 7; ++ox) {
            float acc[8];
#pragma unroll
            for (int j = 0; j < 8; ++j) acc[j] = -INFINITY;
            bool inv = false;

#pragma unroll
            for (int sx = 0; sx < 2; ++sx) {
                int ix = ox * 2 + sx;
                float ttx = (float)ix * (1.0f / 13.0f);
                float in_x = (x1n + ttx * xdn) * 62.0f;
                bool vx = (in_x >= 0.0f) && (in_x <= 62.0f);
                float x0f = floorf(in_x);
                float wx = in_x - x0f;
                int xo0 = (int)fminf(fmaxf(x0f, 0.0f), 62.0f) << 9;       // *512
                int xo1 = (int)fminf(fmaxf(x0f + 1.0f, 0.0f), 62.0f) << 9;

                bool valid = vx && vy;
                if (valid) {
                    f16x8 g00 = *(const f16x8*)(imgc + yb0 + xo0);
                    f16x8 g01 = *(const f16x8*)(imgc + yb0 + xo1);
                    f16x8 g10 = *(const f16x8*)(imgc + yb1 + xo0);
                    f16x8 g11 = *(const f16x8*)(imgc + yb1 + xo1);

                    _Float16 wxh = (_Float16)wx;
                    f16x8 toph = g00 + (g01 - g00) * wxh;   // v_pk_* x-lerp
                    f16x8 both = g10 + (g11 - g10) * wxh;

#pragma unroll
                    for (int j = 0; j < 8; ++j) {           // f32 y-lerp + max
                        float tf = (float)toph[j];
                        float bf = (float)both[j];
                        acc[j] = fmaxf(acc[j], tf + (bf - tf) * wy);
                    }
                } else {
                    inv = true;
                }
            }
            if (inv) {      // invalid samples contribute 0 to the max (rare)
#pragma unroll
                for (int j = 0; j < 8; ++j) acc[j] = fmaxf(acc[j], 0.0f);
            }

            // sy-max across the slot pair: lanes l <-> l^16, LDS pipe not VALU
#pragma unroll
            for (int j = 0; j < 8; ++j) {
                float o = __shfl_xor(acc[j], 16);
                acc[j] = fmaxf(acc[j], o);
            }
            if (!(slot & 1)) {   // even slot writes the final output value
                int pos = oy * 7 + ox;
#pragma unroll
                for (int j = 0; j < 8; ++j)
                    stage[(g * 8 + j) * NP + pos] = acc[j];
            }
        }
    }

    __syncthreads();

    // pure linear flush: stage layout == output layout for this quarter.
    const f32x4* s4 = (const f32x4*)stage;
    f32x4* o4 = (f32x4*)(out + ((n << 9) + (q << 7)) * NP);
    for (int i = t; i < (128 * NP) / 4; i += 256)
        __builtin_nontemporal_store(s4[i], &o4[i]);
}

// ---------------- fallback (ws too small): direct CHW f32 gathers ------------
__global__ __launch_bounds__(256) void roi_pool_chw(
        const float* __restrict__ img,    // CHW
        const float* __restrict__ rois,
        float* __restrict__ out) {
    __shared__ float stage[256 * NP];
    int n = blockIdx.x >> 1;
    int h = blockIdx.x & 1;
    int t = threadIdx.x;
    int c = (h << 8) + t;

    const float* r = rois + n * 5;
    float x1n = (r[1] * 0.0625f) / 62.0f;
    float y1n = (r[2] * 0.0625f) / 37.0f;
    float x2n = (r[3] * 0.0625f) / 62.0f;
    float y2n = (r[4] * 0.0625f) / 37.0f;
    float ydn = y2n - y1n;
    float xdn = x2n - x1n;

    const float* imgc = img + c * HWSZ;

    float wxa[14];
    int   x0a[14], x1a[14];
    int   vxm = 0;
#pragma unroll
    for (int ix = 0; ix < 14; ++ix) {
        float tt = (float)ix * (1.0f / 13.0f);
        float in_x = (x1n + tt * xdn) * 62.0f;
        if (in_x >= 0.0f && in_x <= 62.0f) vxm |= (1 << ix);
        float x0f = floorf(in_x);
        wxa[ix] = in_x - x0f;
        x0a[ix] = (int)fminf(fmaxf(x0f, 0.0f), 62.0f);
        x1a[ix] = (int)fminf(fmaxf(x0f + 1.0f, 0.0f), 62.0f);
    }

#pragma unroll
    for (int oy = 0; oy < 7; ++oy) {
        float row[7];
#pragma unroll
        for (int ox = 0; ox < 7; ++ox) row[ox] = -INFINITY;
#pragma unroll
        for (int sy = 0; sy < 2; ++sy) {
            int iy = oy * 2 + sy;
            float tt = (float)iy * (1.0f / 13.0f);
            float in_y = (y1n + tt * ydn) * 37.0f;
            bool vy = (in_y >= 0.0f) && (in_y <= 37.0f);
            float y0f = floorf(in_y);
            float wy = in_y - y0f;
            int yy0 = (int)fminf(fmaxf(y0f, 0.0f), 37.0f);
            int yy1 = (int)fminf(fmaxf(y0f + 1.0f, 0.0f), 37.0f);
            int yb0 = yy0 * WW;
            int yb1 = yy1 * WW;
#pragma unroll
            for (int ox = 0; ox < 7; ++ox) {
#pragma unroll
                for (int sx = 0; sx < 2; ++sx) {
                    int ix = ox * 2 + sx;
                    float g00 = imgc[yb0 + x0a[ix]];
                    float g01 = imgc[yb0 + x1a[ix]];
                    float g10 = imgc[yb1 + x0a[ix]];
                    float g11 = imgc[yb1 + x1a[ix]];
                    float wx = wxa[ix];
                    float top = g00 + (g01 - g00) * wx;
                    float bot = g10 + (g11 - g10) * wx;
                    float val = top + (bot - top) * wy;
                    bool valid = vy && ((vxm >> ix) & 1);
                    val = valid ? val : 0.0f;
                    row[ox] = fmaxf(row[ox], val);
                }
            }
        }
#pragma unroll
        for (int ox = 0; ox < 7; ++ox)
            stage[t * NP + oy * 7 + ox] = row[ox];
    }

    __syncthreads();
    const float4* s4 = (const float4*)stage;
    float4* o4 = (float4*)(out + ((n << 9) + (h << 8)) * NP);
    for (int i = t; i < (256 * NP) / 4; i += 256)
        o4[i] = s4[i];
}

extern "C" void kernel_launch(void* const* d_in, const int* in_sizes, int n_in,
                              void* d_out, int out_size, void* d_ws, size_t ws_size,
                              hipStream_t stream) {
    const float* bottom = (const float*)d_in[0];
    const float* rois   = (const float*)d_in[1];
    float* out = (float*)d_out;

    const size_t need = (size_t)CC * HWSZ * sizeof(_Float16);  // ~2.45 MB
    if (ws_size >= need) {
        _Float16* img = (_Float16*)d_ws;
        dim3 tg((HWSZ + 63) / 64, CC / 64);   // 38 x 8
        transpose_cvt<<<tg, 256, 0, stream>>>(bottom, img);
        roi_pool_v11<<<NROIS * 4, 256, 0, stream>>>(img, rois, out);
    } else {
        roi_pool_chw<<<NROIS * 2, 256, 0, stream>>>(bottom, rois, out);
    }
}

// Round 7
// 145.174 us; speedup vs baseline: 1.1269x; 1.0554x over previous
//
#include <hip/hip_runtime.h>
#include <math.h>

#define CC 512
#define HH 38
#define WW 63
#define HWSZ (HH * WW)
#define NROIS 1024
#define NP 49              // 7x7 pooled positions

typedef float    f32x4 __attribute__((ext_vector_type(4)));
typedef _Float16 f16x8 __attribute__((ext_vector_type(8)));
typedef _Float16 f16x2 __attribute__((ext_vector_type(2)));

// ------------- transpose + convert: CHW f32 (512,2394) -> HWC fp16 (2394,512)
__global__ __launch_bounds__(256) void transpose_cvt(
        const float* __restrict__ src, _Float16* __restrict__ dst) {
    __shared__ float tile[64][65];
    int s0 = blockIdx.x * 64;
    int c0 = blockIdx.y * 64;
    int tx = threadIdx.x & 63;
    int ty = threadIdx.x >> 6;

#pragma unroll
    for (int k = 0; k < 16; ++k) {
        int c = ty * 16 + k;
        int s = s0 + tx;
        float v = (s < HWSZ) ? src[(c0 + c) * HWSZ + s] : 0.0f;
        tile[tx][c] = v;
    }
    __syncthreads();

    int u = threadIdx.x & 31;       // channel pair
    int vv = threadIdx.x >> 5;      // row group
#pragma unroll
    for (int k = 0; k < 8; ++k) {
        int s = vv * 8 + k;
        if (s0 + s < HWSZ) {
            f16x2 h;
            h[0] = (_Float16)tile[s][2 * u];
            h[1] = (_Float16)tile[s][2 * u + 1];
            *(f16x2*)(dst + (size_t)(s0 + s) * CC + c0 + 2 * u) = h;
        }
    }
}

// ---------------- main kernel v12 --------------------------------------------
// v11 structure unchanged (slot = sample row iy, uniform-validity branch,
// shfl_xor(16) sy-max across slot pairs, output-layout stage, linear
// nontemporal flush). v12 finishes the fp16 datapath: y-lerp and max in
// packed f16 (v_pk_fma_f16 / v_pk_max_f16, 2 ch/op); acc is f16x8 = 4 dwords
// (shfl moves 4 dwords, not 8); f16->f32 conversion happens ONCE, in even
// slots only, at stage-write (8 cvt/ox vs v11's 32 cvt + 16 f32 ops + 8 f32
// max per ox). ~25-30% of remaining inner-loop VALU removed at identical
// bytes. Extra f16 rounding on the y-lerp: ~1 ulp_h, absmax expected to stay
// well under the (already-passed) 0.03125 scale.
__global__ __launch_bounds__(256) void roi_pool_v12(
        const _Float16* __restrict__ img,  // HWC fp16 (2394, 512)
        const float* __restrict__ rois,    // (N, 5)
        float* __restrict__ out) {         // (N, 512, 7, 7)
    __shared__ float stage[128 * NP];      // 25088 B, output layout [c][p]

    int n = blockIdx.x >> 2;              // wave-uniform
    int q = blockIdx.x & 3;
    int t = threadIdx.x;
    int g = t & 15;                       // channel oct within quarter
    int slot = t >> 4;                    // 0..15; slots 0..13 = sample row iy

    const float* r = rois + n * 5;
    float x1n = (r[1] * 0.0625f) / 62.0f;
    float y1n = (r[2] * 0.0625f) / 37.0f;
    float x2n = (r[3] * 0.0625f) / 62.0f;
    float y2n = (r[4] * 0.0625f) / 37.0f;
    float ydn = y2n - y1n;
    float xdn = x2n - x1n;

    if (slot < 14) {
        int iy = slot;
        int oy = iy >> 1;
        // this slot's y-params (one sample row)
        float tty = (float)iy * (1.0f / 13.0f);
        float in_y = (y1n + tty * ydn) * 37.0f;
        bool vy = (in_y >= 0.0f) && (in_y <= 37.0f);
        float y0f = floorf(in_y);
        _Float16 wyh = (_Float16)(in_y - y0f);
        int yb0 = (int)fminf(fmaxf(y0f, 0.0f), 37.0f) * (WW * CC);        // halfs
        int yb1 = (int)fminf(fmaxf(y0f + 1.0f, 0.0f), 37.0f) * (WW * CC);

        const _Float16* imgc = img + (q << 7) + (g << 3);   // +q*128 +8g halfs

#pragma unroll
        for (int ox = 0; ox < 7; ++ox) {
            f16x8 acc;
#pragma unroll
            for (int j = 0; j < 8; ++j) acc[j] = (_Float16)(-INFINITY);
            bool inv = false;

#pragma unroll
            for (int sx = 0; sx < 2; ++sx) {
                int ix = ox * 2 + sx;
                float ttx = (float)ix * (1.0f / 13.0f);
                float in_x = (x1n + ttx * xdn) * 62.0f;
                bool vx = (in_x >= 0.0f) && (in_x <= 62.0f);
                float x0f = floorf(in_x);
                float wx = in_x - x0f;
                int xo0 = (int)fminf(fmaxf(x0f, 0.0f), 62.0f) << 9;       // *512
                int xo1 = (int)fminf(fmaxf(x0f + 1.0f, 0.0f), 62.0f) << 9;

                bool valid = vx && vy;
                if (valid) {
                    f16x8 g00 = *(const f16x8*)(imgc + yb0 + xo0);
                    f16x8 g01 = *(const f16x8*)(imgc + yb0 + xo1);
                    f16x8 g10 = *(const f16x8*)(imgc + yb1 + xo0);
                    f16x8 g11 = *(const f16x8*)(imgc + yb1 + xo1);

                    _Float16 wxh = (_Float16)wx;
                    f16x8 toph = g00 + (g01 - g00) * wxh;   // v_pk_* x-lerp
                    f16x8 both = g10 + (g11 - g10) * wxh;
                    f16x8 val  = toph + (both - toph) * wyh; // v_pk_* y-lerp
                    acc = __builtin_elementwise_max(acc, val); // v_pk_max_f16
                } else {
                    inv = true;
                }
            }
            if (inv) {      // invalid samples contribute 0 to the max (rare)
                f16x8 z;
#pragma unroll
                for (int j = 0; j < 8; ++j) z[j] = (_Float16)0.0f;
                acc = __builtin_elementwise_max(acc, z);
            }

            // sy-max across the slot pair: lanes l <-> l^16, 4 dwords only
            int4 ai = __builtin_bit_cast(int4, acc);
            ai.x = __shfl_xor(ai.x, 16);
            ai.y = __shfl_xor(ai.y, 16);
            ai.z = __shfl_xor(ai.z, 16);
            ai.w = __shfl_xor(ai.w, 16);
            f16x8 other = __builtin_bit_cast(f16x8, ai);
            acc = __builtin_elementwise_max(acc, other);

            if (!(slot & 1)) {   // even slot converts + writes final outputs
                int pos = oy * 7 + ox;
#pragma unroll
                for (int j = 0; j < 8; ++j)
                    stage[(g * 8 + j) * NP + pos] = (float)acc[j];
            }
        }
    }

    __syncthreads();

    // pure linear flush: stage layout == output layout for this quarter.
    const f32x4* s4 = (const f32x4*)stage;
    f32x4* o4 = (f32x4*)(out + ((n << 9) + (q << 7)) * NP);
    for (int i = t; i < (128 * NP) / 4; i += 256)
        __builtin_nontemporal_store(s4[i], &o4[i]);
}

// ---------------- fallback (ws too small): direct CHW f32 gathers ------------
__global__ __launch_bounds__(256) void roi_pool_chw(
        const float* __restrict__ img,    // CHW
        const float* __restrict__ rois,
        float* __restrict__ out) {
    __shared__ float stage[256 * NP];
    int n = blockIdx.x >> 1;
    int h = blockIdx.x & 1;
    int t = threadIdx.x;
    int c = (h << 8) + t;

    const float* r = rois + n * 5;
    float x1n = (r[1] * 0.0625f) / 62.0f;
    float y1n = (r[2] * 0.0625f) / 37.0f;
    float x2n = (r[3] * 0.0625f) / 62.0f;
    float y2n = (r[4] * 0.0625f) / 37.0f;
    float ydn = y2n - y1n;
    float xdn = x2n - x1n;

    const float* imgc = img + c * HWSZ;

    float wxa[14];
    int   x0a[14], x1a[14];
    int   vxm = 0;
#pragma unroll
    for (int ix = 0; ix < 14; ++ix) {
        float tt = (float)ix * (1.0f / 13.0f);
        float in_x = (x1n + tt * xdn) * 62.0f;
        if (in_x >= 0.0f && in_x <= 62.0f) vxm |= (1 << ix);
        float x0f = floorf(in_x);
        wxa[ix] = in_x - x0f;
        x0a[ix] = (int)fminf(fmaxf(x0f, 0.0f), 62.0f);
        x1a[ix] = (int)fminf(fmaxf(x0f + 1.0f, 0.0f), 62.0f);
    }

#pragma unroll
    for (int oy = 0; oy < 7; ++oy) {
        float row[7];
#pragma unroll
        for (int ox = 0; ox < 7; ++ox) row[ox] = -INFINITY;
#pragma unroll
        for (int sy = 0; sy < 2; ++sy) {
            int iy = oy * 2 + sy;
            float tt = (float)iy * (1.0f / 13.0f);
            float in_y = (y1n + tt * ydn) * 37.0f;
            bool vy = (in_y >= 0.0f) && (in_y <= 37.0f);
            float y0f = floorf(in_y);
            float wy = in_y - y0f;
            int yy0 = (int)fminf(fmaxf(y0f, 0.0f), 37.0f);
            int yy1 = (int)fminf(fmaxf(y0f + 1.0f, 0.0f), 37.0f);
            int yb0 = yy0 * WW;
            int yb1 = yy1 * WW;
#pragma unroll
            for (int ox = 0; ox < 7; ++ox) {
#pragma unroll
                for (int sx = 0; sx < 2; ++sx) {
                    int ix = ox * 2 + sx;
                    float g00 = imgc[yb0 + x0a[ix]];
                    float g01 = imgc[yb0 + x1a[ix]];
                    float g10 = imgc[yb1 + x0a[ix]];
                    float g11 = imgc[yb1 + x1a[ix]];
                    float wx = wxa[ix];
                    float top = g00 + (g01 - g00) * wx;
                    float bot = g10 + (g11 - g10) * wx;
                    float val = top + (bot - top) * wy;
                    bool valid = vy && ((vxm >> ix) & 1);
                    val = valid ? val : 0.0f;
                    row[ox] = fmaxf(row[ox], val);
                }
            }
        }
#pragma unroll
        for (int ox = 0; ox < 7; ++ox)
            stage[t * NP + oy * 7 + ox] = row[ox];
    }

    __syncthreads();
    const float4* s4 = (const float4*)stage;
    float4* o4 = (float4*)(out + ((n << 9) + (h << 8)) * NP);
    for (int i = t; i < (256 * NP) / 4; i += 256)
        o4[i] = s4[i];
}

extern "C" void kernel_launch(void* const* d_in, const int* in_sizes, int n_in,
                              void* d_out, int out_size, void* d_ws, size_t ws_size,
                              hipStream_t stream) {
    const float* bottom = (const float*)d_in[0];
    const float* rois   = (const float*)d_in[1];
    float* out = (float*)d_out;

    const size_t need = (size_t)CC * HWSZ * sizeof(_Float16);  // ~2.45 MB
    if (ws_size >= need) {
        _Float16* img = (_Float16*)d_ws;
        dim3 tg((HWSZ + 63) / 64, CC / 64);   // 38 x 8
        transpose_cvt<<<tg, 256, 0, stream>>>(bottom, img);
        roi_pool_v12<<<NROIS * 4, 256, 0, stream>>>(img, rois, out);
    } else {
        roi_pool_chw<<<NROIS * 2, 256, 0, stream>>>(bottom, rois, out);
    }
}

// Round 8
// 137.877 us; speedup vs baseline: 1.1865x; 1.0529x over previous
//
#include <hip/hip_runtime.h>
#include <math.h>

#define CC 512
#define HH 38
#define WW 63
#define HWSZ (HH * WW)
#define NROIS 1024
#define NP 49              // 7x7 pooled positions

typedef float    f32x4 __attribute__((ext_vector_type(4)));
typedef _Float16 f16x8 __attribute__((ext_vector_type(8)));
typedef _Float16 f16x4 __attribute__((ext_vector_type(4)));

// ------------- transpose + convert: CHW f32 (512,2394) -> HWC fp16 (2394,512)
__global__ __launch_bounds__(256) void transpose_cvt(
        const float* __restrict__ src, _Float16* __restrict__ dst) {
    __shared__ float tile[64][65];
    int s0 = blockIdx.x * 64;
    int c0 = blockIdx.y * 64;
    int tx = threadIdx.x & 63;
    int ty = threadIdx.x >> 6;

#pragma unroll
    for (int k = 0; k < 16; ++k) {
        int c = ty * 16 + k;
        int s = s0 + tx;
        float v = (s < HWSZ) ? src[(c0 + c) * HWSZ + s] : 0.0f;
        tile[tx][c] = v;
    }
    __syncthreads();

    // store phase: f16x4 (8B) stores -- 16 ch-quads x 16 row-groups of 4
    int u = threadIdx.x & 15;       // channel quad (4u..4u+3)
    int vv = threadIdx.x >> 4;      // row group
#pragma unroll
    for (int k = 0; k < 4; ++k) {
        int s = vv * 4 + k;
        if (s0 + s < HWSZ) {
            f16x4 h;
#pragma unroll
            for (int j = 0; j < 4; ++j) h[j] = (_Float16)tile[s][4 * u + j];
            *(f16x4*)(dst + (size_t)(s0 + s) * CC + c0 + 4 * u) = h;
        }
    }
}

// ---------------- main kernel v13 --------------------------------------------
// v12 structure unchanged (slot = sample row iy, uniform-validity branch,
// shfl_xor(16) sy-max across slot pairs, output-layout stage, linear
// nontemporal flush). v13 cuts the remaining VALU fat:
//  - 4-weight FMA bilinear: val = g00*w00 + g01*w01 + g10*w10 + g11*w11 with
//    w = (1-wx,wx)x(1-wy,wy) outer product (5 scalar f16 ops/sx). 16 pk-ops
//    + 4 pk-max vs v12's 28 -- ~30% fewer packed instructions, same math.
//  - offset computation moved INSIDE the valid branch; x0 needs no clamp
//    when valid (floor(in_x) in [0,62]); x1 = min(x0+1, 62) only.
//  - in_x via one fma against hoisted A=x1n*62, B=xdn*62.
__global__ __launch_bounds__(256) void roi_pool_v13(
        const _Float16* __restrict__ img,  // HWC fp16 (2394, 512)
        const float* __restrict__ rois,    // (N, 5)
        float* __restrict__ out) {         // (N, 512, 7, 7)
    __shared__ float stage[128 * NP];      // 25088 B, output layout [c][p]

    int n = blockIdx.x >> 2;              // wave-uniform
    int q = blockIdx.x & 3;
    int t = threadIdx.x;
    int g = t & 15;                       // channel oct within quarter
    int slot = t >> 4;                    // 0..15; slots 0..13 = sample row iy

    const float* r = rois + n * 5;
    float x1n = (r[1] * 0.0625f) / 62.0f;
    float y1n = (r[2] * 0.0625f) / 37.0f;
    float x2n = (r[3] * 0.0625f) / 62.0f;
    float y2n = (r[4] * 0.0625f) / 37.0f;
    float ydn = y2n - y1n;
    float xdn = x2n - x1n;

    // hoisted x-line coefficients: in_x = A + ttx * B
    float A = x1n * 62.0f;
    float B = xdn * 62.0f;

    if (slot < 14) {
        int iy = slot;
        int oy = iy >> 1;
        // this slot's y-params (one sample row)
        float tty = (float)iy * (1.0f / 13.0f);
        float in_y = (y1n + tty * ydn) * 37.0f;
        bool vy = (in_y >= 0.0f) && (in_y <= 37.0f);
        float y0f = floorf(in_y);
        _Float16 wyh = (_Float16)(in_y - y0f);
        _Float16 myh = (_Float16)1.0f - wyh;
        int yb0 = (int)fminf(fmaxf(y0f, 0.0f), 37.0f) * (WW * CC);        // halfs
        int yb1 = (int)fminf(fmaxf(y0f + 1.0f, 0.0f), 37.0f) * (WW * CC);

        const _Float16* imgc = img + (q << 7) + (g << 3);   // +q*128 +8g halfs

#pragma unroll
        for (int ox = 0; ox < 7; ++ox) {
            f16x8 acc;
#pragma unroll
            for (int j = 0; j < 8; ++j) acc[j] = (_Float16)(-INFINITY);
            bool inv = false;

#pragma unroll
            for (int sx = 0; sx < 2; ++sx) {
                int ix = ox * 2 + sx;
                float ttx = (float)ix * (1.0f / 13.0f);
                float in_x = fmaf(ttx, B, A);
                bool valid = vy && (in_x >= 0.0f) && (in_x <= 62.0f);
                if (valid) {
                    float x0f = floorf(in_x);
                    _Float16 wxh = (_Float16)(in_x - x0f);
                    _Float16 mxh = (_Float16)1.0f - wxh;
                    int x0i = (int)x0f;                   // in [0,62], no clamp
                    int x1i = min(x0i + 1, 62);
                    int xo0 = x0i << 9;                   // * CC halfs
                    int xo1 = x1i << 9;

                    f16x8 g00 = *(const f16x8*)(imgc + yb0 + xo0);
                    f16x8 g01 = *(const f16x8*)(imgc + yb0 + xo1);
                    f16x8 g10 = *(const f16x8*)(imgc + yb1 + xo0);
                    f16x8 g11 = *(const f16x8*)(imgc + yb1 + xo1);

                    _Float16 w00 = mxh * myh;             // 4 corner weights
                    _Float16 w01 = wxh * myh;
                    _Float16 w10 = mxh * wyh;
                    _Float16 w11 = wxh * wyh;

                    f16x8 val = g00 * w00;                // 4x v_pk_mul/fma
                    val = g01 * w01 + val;
                    val = g10 * w10 + val;
                    val = g11 * w11 + val;
                    acc = __builtin_elementwise_max(acc, val);
                } else {
                    inv = true;
                }
            }
            if (inv) {      // invalid samples contribute 0 to the max (rare)
                f16x8 z;
#pragma unroll
                for (int j = 0; j < 8; ++j) z[j] = (_Float16)0.0f;
                acc = __builtin_elementwise_max(acc, z);
            }

            // sy-max across the slot pair: lanes l <-> l^16, 4 dwords only
            int4 ai = __builtin_bit_cast(int4, acc);
            ai.x = __shfl_xor(ai.x, 16);
            ai.y = __shfl_xor(ai.y, 16);
            ai.z = __shfl_xor(ai.z, 16);
            ai.w = __shfl_xor(ai.w, 16);
            f16x8 other = __builtin_bit_cast(f16x8, ai);
            acc = __builtin_elementwise_max(acc, other);

            if (!(slot & 1)) {   // even slot converts + writes final outputs
                int pos = oy * 7 + ox;
#pragma unroll
                for (int j = 0; j < 8; ++j)
                    stage[(g * 8 + j) * NP + pos] = (float)acc[j];
            }
        }
    }

    __syncthreads();

    // pure linear flush: stage layout == output layout for this quarter.
    const f32x4* s4 = (const f32x4*)stage;
    f32x4* o4 = (f32x4*)(out + ((n << 9) + (q << 7)) * NP);
    for (int i = t; i < (128 * NP) / 4; i += 256)
        __builtin_nontemporal_store(s4[i], &o4[i]);
}

// ---------------- fallback (ws too small): direct CHW f32 gathers ------------
__global__ __launch_bounds__(256) void roi_pool_chw(
        const float* __restrict__ img,    // CHW
        const float* __restrict__ rois,
        float* __restrict__ out) {
    __shared__ float stage[256 * NP];
    int n = blockIdx.x >> 1;
    int h = blockIdx.x & 1;
    int t = threadIdx.x;
    int c = (h << 8) + t;

    const float* r = rois + n * 5;
    float x1n = (r[1] * 0.0625f) / 62.0f;
    float y1n = (r[2] * 0.0625f) / 37.0f;
    float x2n = (r[3] * 0.0625f) / 62.0f;
    float y2n = (r[4] * 0.0625f) / 37.0f;
    float ydn = y2n - y1n;
    float xdn = x2n - x1n;

    const float* imgc = img + c * HWSZ;

    float wxa[14];
    int   x0a[14], x1a[14];
    int   vxm = 0;
#pragma unroll
    for (int ix = 0; ix < 14; ++ix) {
        float tt = (float)ix * (1.0f / 13.0f);
        float in_x = (x1n + tt * xdn) * 62.0f;
        if (in_x >= 0.0f && in_x <= 62.0f) vxm |= (1 << ix);
        float x0f = floorf(in_x);
        wxa[ix] = in_x - x0f;
        x0a[ix] = (int)fminf(fmaxf(x0f, 0.0f), 62.0f);
        x1a[ix] = (int)fminf(fmaxf(x0f + 1.0f, 0.0f), 62.0f);
    }

#pragma unroll
    for (int oy = 0; oy < 7; ++oy) {
        float row[7];
#pragma unroll
        for (int ox = 0; ox < 7; ++ox) row[ox] = -INFINITY;
#pragma unroll
        for (int sy = 0; sy < 2; ++sy) {
            int iy = oy * 2 + sy;
            float tt = (float)iy * (1.0f / 13.0f);
            float in_y = (y1n + tt * ydn) * 37.0f;
            bool vy = (in_y >= 0.0f) && (in_y <= 37.0f);
            float y0f = floorf(in_y);
            float wy = in_y - y0f;
            int yy0 = (int)fminf(fmaxf(y0f, 0.0f), 37.0f);
            int yy1 = (int)fminf(fmaxf(y0f + 1.0f, 0.0f), 37.0f);
            int yb0 = yy0 * WW;
            int yb1 = yy1 * WW;
#pragma unroll
            for (int ox = 0; ox < 7; ++ox) {
#pragma unroll
                for (int sx = 0; sx < 2; ++sx) {
                    int ix = ox * 2 + sx;
                    float g00 = imgc[yb0 + x0a[ix]];
                    float g01 = imgc[yb0 + x1a[ix]];
                    float g10 = imgc[yb1 + x0a[ix]];
                    float g11 = imgc[yb1 + x1a[ix]];
                    float wx = wxa[ix];
                    float top = g00 + (g01 - g00) * wx;
                    float bot = g10 + (g11 - g10) * wx;
                    float val = top + (bot - top) * wy;
                    bool valid = vy && ((vxm >> ix) & 1);
                    val = valid ? val : 0.0f;
                    row[ox] = fmaxf(row[ox], val);
                }
            }
        }
#pragma unroll
        for (int ox = 0; ox < 7; ++ox)
            stage[t * NP + oy * 7 + ox] = row[ox];
    }

    __syncthreads();
    const float4* s4 = (const float4*)stage;
    float4* o4 = (float4*)(out + ((n << 9) + (h << 8)) * NP);
    for (int i = t; i < (256 * NP) / 4; i += 256)
        o4[i] = s4[i];
}

extern "C" void kernel_launch(void* const* d_in, const int* in_sizes, int n_in,
                              void* d_out, int out_size, void* d_ws, size_t ws_size,
                              hipStream_t stream) {
    const float* bottom = (const float*)d_in[0];
    const float* rois   = (const float*)d_in[1];
    float* out = (float*)d_out;

    const size_t need = (size_t)CC * HWSZ * sizeof(_Float16);  // ~2.45 MB
    if (ws_size >= need) {
        _Float16* img = (_Float16*)d_ws;
        dim3 tg((HWSZ + 63) / 64, CC / 64);   // 38 x 8
        transpose_cvt<<<tg, 256, 0, stream>>>(bottom, img);
        roi_pool_v13<<<NROIS * 4, 256, 0, stream>>>(img, rois, out);
    } else {
        roi_pool_chw<<<NROIS * 2, 256, 0, stream>>>(bottom, rois, out);
    }
}